// Round 8
// baseline (326.284 us; speedup 1.0000x reference)
//
#include <hip/hip_runtime.h>
#include <stdint.h>

typedef __attribute__((ext_vector_type(8))) short bf16x8;   // 8 bf16 = 4 VGPRs
typedef __attribute__((ext_vector_type(4))) float f32x4;
typedef unsigned short u16;

#define NUM_B 4
#define SEQ   2048
#define DM    1024
#define NH    16
#define DH    64
#define M_TOT (NUM_B * SEQ)   // 8192

__device__ __forceinline__ float bf2f(u16 u) {
    union { unsigned int i; float f; } c; c.i = ((unsigned int)u) << 16; return c.f;
}
__device__ __forceinline__ u16 f2bf(float f) {
    union { float f; unsigned int i; } c; c.f = f;
    unsigned int u = c.i;
    return (u16)((u + 0x7FFFu + ((u >> 16) & 1u)) >> 16);  // RNE
}
__device__ __forceinline__ unsigned int pack2(float a, float b) {
    return (unsigned int)f2bf(a) | ((unsigned int)f2bf(b) << 16);
}

#if __has_builtin(__builtin_amdgcn_exp2f)
#define EXP2F __builtin_amdgcn_exp2f
#else
#define EXP2F exp2f
#endif

#define GLOAD_LDS16(g, l)                                                     \
    __builtin_amdgcn_global_load_lds(                                         \
        (const __attribute__((address_space(1))) void*)(g),                   \
        (__attribute__((address_space(3))) void*)(l), 16, 0, 0)

// ---------------------------------------------------------------------------
// R16 (verified win): fused detect + 5-tensor convert in ONE launch.
// ---------------------------------------------------------------------------
__global__ void convert_all(const void* __restrict__ x,
                            const void* __restrict__ wqkv,
                            const void* __restrict__ bqkv,
                            const void* __restrict__ wout,
                            const void* __restrict__ bout,
                            u16* __restrict__ xb, u16* __restrict__ wqkvb,
                            u16* __restrict__ bqkvb, u16* __restrict__ woutb,
                            u16* __restrict__ boutb, int* __restrict__ flag)
{
    // --- per-block dtype detection (R4-verified heuristic) ---
    __shared__ int cnt;
    if (threadIdx.x == 0) cnt = 0;
    __syncthreads();
    int local = 0;
    const u16* xs = (const u16*)x;
    for (int i = threadIdx.x; i < 4096; i += 256) {
        const u16 v = xs[i];
        const int e = (v >> 7) & 0xFF;
        if (v == 0 || (e >= 110 && e <= 145)) local++;
    }
    atomicAdd(&cnt, local);
    __syncthreads();
    const int isf32 = (cnt >= 3686) ? 0 : 1;   // 0 = bf16 inputs, 1 = fp32
    if (blockIdx.x == 0 && threadIdx.x == 0) *flag = isf32;

    // --- 5-segment virtual index space, unit = 8 elements (16 B out) ---
    const long U0 = 1048576;           // x      8388608 elems
    const long U1 = U0 + 393216;       // w_qkv  3145728
    const long U2 = U1 + 384;          // b_qkv  3072
    const long U3 = U2 + 131072;       // w_out  1048576
    const long U4 = U3 + 128;          // b_out  1024

    for (long u = (long)blockIdx.x * 256 + threadIdx.x; u < U4;
         u += (long)gridDim.x * 256) {
        const void* src; u16* dst; long off;
        if (u < U0)      { src = x;    dst = xb;    off = u; }
        else if (u < U1) { src = wqkv; dst = wqkvb; off = u - U0; }
        else if (u < U2) { src = bqkv; dst = bqkvb; off = u - U1; }
        else if (u < U3) { src = wout; dst = woutb; off = u - U2; }
        else             { src = bout; dst = boutb; off = u - U3; }
        const long i = off * 8;
        if (isf32) {
            const float* f = (const float*)src;
            float4 a = *(const float4*)(f + i);
            float4 b = *(const float4*)(f + i + 4);
            uint4 o;
            o.x = pack2(a.x, a.y); o.y = pack2(a.z, a.w);
            o.z = pack2(b.x, b.y); o.w = pack2(b.z, b.w);
            *(uint4*)(dst + i) = o;
        } else {
            *(uint4*)(dst + i) = ((const uint4*)src)[off];
        }
    }
}

// ---------------------------------------------------------------------------
// bf16 GEMM — R17: BK=64 (barrier amortization).
// R14/R16 counters: 100.6 us, MfmaUtil 20.7%, VALUBusy 14%, HBM 16%,
// ~2 blocks/CU -> ~500+ cy exposed barrier-drain stall per K-step, x33.
// R15 (dbuf) was null: moving the drain doesn't help; T2 swizzle is
// regime-gated null at 2-phase. So AMORTIZE: stage two 32-wide chunks per
// step (layout [khalf][128][32], each half bit-identical to the verified
// BK=32 layout), run 32 MFMA per barrier, 17 barriers instead of 33.
// Fragments read per-half to keep live VGPR flat. LDS 16->32 KB.
// MODE 0: scatter Q,K -> [bh][s][dh]; V -> transposed [bh][dh][s].
// MODE 1: plain store, fp32 or bf16 per *outf32.
// ---------------------------------------------------------------------------
template <int MODE, int N_TOT>
__global__ __launch_bounds__(256) void gemm_bt(
    const u16* __restrict__ A, const u16* __restrict__ Bm,
    const u16* __restrict__ bias,
    void* __restrict__ out0v, u16* __restrict__ out1, u16* __restrict__ out2,
    const int* __restrict__ outf32, long out_off)
{
    __shared__ __align__(16) u16 As[2 * 128 * 32];   // [khalf][128 rows][32]
    __shared__ __align__(16) u16 Bs[2 * 128 * 32];
    const int K = 1024;

    const int tid  = threadIdx.x;
    const int wave = tid >> 6;
    const int lane = tid & 63;
    const int l15  = lane & 15;
    const int quad = lane >> 4;

    const int m0 = blockIdx.y * 128;
    const int n0 = blockIdx.x * 128;
    const int wm = (wave >> 1) * 64;
    const int wn = (wave & 1) * 64;

    const int srow = lane >> 2;
    const int soff = (lane & 3) * 8;

    f32x4 acc[4][4];
#pragma unroll
    for (int i = 0; i < 4; ++i)
#pragma unroll
        for (int j = 0; j < 4; ++j)
            acc[i][j] = (f32x4){0.f, 0.f, 0.f, 0.f};

    for (int k0 = 0; k0 < K; k0 += 64) {
        // stage both 32-wide halves of the 128x64 tiles (8 gloads/wave)
#pragma unroll
        for (int h = 0; h < 2; ++h) {
#pragma unroll
            for (int r = 0; r < 2; ++r) {
                const int chunk = wave * 2 + r;
                const int row   = chunk * 16 + srow;
                GLOAD_LDS16(&A[(size_t)(m0 + row) * K + k0 + h * 32 + soff],
                            &As[h * 4096 + chunk * 512]);
                GLOAD_LDS16(&Bm[(size_t)(n0 + row) * K + k0 + h * 32 + soff],
                            &Bs[h * 4096 + chunk * 512]);
            }
        }
        __syncthreads();

#pragma unroll
        for (int h = 0; h < 2; ++h) {
            bf16x8 af[4], bfv[4];
#pragma unroll
            for (int i = 0; i < 4; ++i)
                af[i] = *(const bf16x8*)(&As[h * 4096 + (wm + i * 16 + l15) * 32 + quad * 8]);
#pragma unroll
            for (int j = 0; j < 4; ++j)
                bfv[j] = *(const bf16x8*)(&Bs[h * 4096 + (wn + j * 16 + l15) * 32 + quad * 8]);

#pragma unroll
            for (int i = 0; i < 4; ++i)
#pragma unroll
                for (int j = 0; j < 4; ++j)
                    acc[i][j] = __builtin_amdgcn_mfma_f32_16x16x32_bf16(
                        af[i], bfv[j], acc[i][j], 0, 0, 0);
        }
        __syncthreads();
    }

    const int of32 = outf32 ? *outf32 : 0;
#pragma unroll
    for (int j = 0; j < 4; ++j) {
        const int n  = n0 + wn + j * 16 + l15;
        const float bv = bf2f(bias[n]);
#pragma unroll
        for (int i = 0; i < 4; ++i) {
#pragma unroll
            for (int reg = 0; reg < 4; ++reg) {
                const int m = m0 + wm + i * 16 + quad * 4 + reg;
                const float v = acc[i][j][reg] + bv;
                if (MODE == 0) {
                    const int sel = n >> 10;         // 0=Q 1=K 2=V
                    const int h   = (n >> 6) & 15;
                    const int dh  = n & 63;
                    const int b   = m >> 11;
                    const int s   = m & 2047;
                    if (sel == 2) {
                        out2[((size_t)((b * NH + h) * DH + dh)) * SEQ + s] = f2bf(v);
                    } else {
                        u16* dst = (sel == 0) ? (u16*)out0v : out1;
                        dst[((size_t)((b * NH + h) * SEQ + s)) * DH + dh] = f2bf(v);
                    }
                } else {
                    if (of32)
                        ((float*)out0v)[out_off + (size_t)m * N_TOT + n] = v;
                    else
                        ((u16*)out0v)[out_off + (size_t)m * N_TOT + n] = f2bf(v);
                }
            }
        }
    }
}

// ---------------------------------------------------------------------------
// Flash attention, causal — R14 (verified best). R9 structure + CU
// load-balance y-permutation + exp2 fold. UNCHANGED.
// ---------------------------------------------------------------------------
__global__ __launch_bounds__(256) void attn_fwd(
    const u16* __restrict__ Qb, const u16* __restrict__ Kb,
    const u16* __restrict__ Vt, u16* __restrict__ ctx)
{
    __shared__ __align__(16) u16 Ks[2][2048];          // fragment-major K tile
    __shared__ __align__(16) u16 Vs[2][2048];          // fragment-major V tile
    __shared__ __align__(16) short Pbuf[4][2][16 * 40];

    const int tid  = threadIdx.x;
    const int wave = tid >> 6;
    const int lane = tid & 63;
    const int l15  = lane & 15;
    const int quad = lane >> 4;

    const int bh = blockIdx.x;
    // CU load-balance permutation of the q-tile index (bijective on 0..15):
    // {a, a+4, a+8, a+12} -> {a, 7-a, 8+a, 15-a}; per-CU staged-tile sum
    // becomes 136 for every CU (was 112..160).
    const int ya = blockIdx.y & 3, yk = blockIdx.y >> 2;
    const int yb = (yk == 0) ? ya : (yk == 1) ? 7 - ya : (yk == 2) ? 8 + ya : 15 - ya;

    const int q0 = yb * 128;                  // block's 128 q-rows
    const int qrowA = q0 + wave * 32;         // wave's frag-0 rows
    const size_t base  = (size_t)bh * SEQ * DH;   // Q,K
    const size_t baseT = (size_t)bh * DH * SEQ;   // Vt
    const float sc_l2e = 0.18033688011112042f;    // (1/8) * log2(e)

    // Q fragments: [frag][dh-half]
    bf16x8 qf[2][2];
#pragma unroll
    for (int f = 0; f < 2; ++f)
#pragma unroll
        for (int c = 0; c < 2; ++c)
            qf[f][c] = *(const bf16x8*)(&Qb[base + (size_t)(qrowA + f * 16 + l15) * DH + c * 32 + quad * 8]);

    f32x4 acc[2][4];
#pragma unroll
    for (int f = 0; f < 2; ++f)
#pragma unroll
        for (int j = 0; j < 4; ++j) acc[f][j] = (f32x4){0.f, 0.f, 0.f, 0.f};
    float lsum[2][4] = {{0.f, 0.f, 0.f, 0.f}, {0.f, 0.f, 0.f, 0.f}};

    const int ktend = yb * 4 + 3;     // block-uniform trip count
    const int mkt   = yb * 4 + wave;  // wave's diagonal tile (k0 == qrowA)

    // staging source offsets (fragment-major; see R9 header)
    const int k_r = (wave & 1) * 16 + l15;            // key row within tile
    const int k_c = ((wave >> 1) * 4 + quad) * 8;     // dh elem offset
    const int v_dh = wave * 16 + l15;                 // dh row
    const int v_k  = quad * 8;                        // key elem offset

    {   // stage tile 0 into buf 0
        GLOAD_LDS16(&Kb[base + (size_t)k_r * DH + k_c], &Ks[0][wave * 512]);
        GLOAD_LDS16(&Vt[baseT + (size_t)v_dh * SEQ + v_k], &Vs[0][wave * 512]);
    }

    for (int kt = 0; kt <= ktend; ++kt) {
        const int cur = kt & 1;
        __syncthreads();   // drains stage(kt) DMA + prior ds_reads of cur buf

        if (kt + 1 <= ktend) {   // prefetch next tile into the other buffer
            const int nk0 = (kt + 1) * 32;
            GLOAD_LDS16(&Kb[base + (size_t)(nk0 + k_r) * DH + k_c],
                        &Ks[1 - cur][wave * 512]);
            GLOAD_LDS16(&Vt[baseT + (size_t)v_dh * SEQ + nk0 + v_k],
                        &Vs[1 - cur][wave * 512]);
        }

        if (kt <= mkt) {         // wave-uniform causal skip
            // fragment reads: all lane-consecutive b128 (conflict-free)
            bf16x8 kf[2][2], vfr[4];
#pragma unroll
            for (int half = 0; half < 2; ++half)
#pragma unroll
                for (int c = 0; c < 2; ++c)
                    kf[half][c] = *(const bf16x8*)(&Ks[cur][(c * 2 + half) * 512 + lane * 8]);
#pragma unroll
            for (int j = 0; j < 4; ++j)
                vfr[j] = *(const bf16x8*)(&Vs[cur][j * 512 + lane * 8]);

            const int diag = (kt == mkt);
#pragma unroll
            for (int f = 0; f < 2; ++f) {
                f32x4 sc0 = (f32x4){0.f, 0.f, 0.f, 0.f};
                f32x4 sc1 = (f32x4){0.f, 0.f, 0.f, 0.f};
                sc0 = __builtin_amdgcn_mfma_f32_16x16x32_bf16(qf[f][0], kf[0][0], sc0, 0, 0, 0);
                sc0 = __builtin_amdgcn_mfma_f32_16x16x32_bf16(qf[f][1], kf[0][1], sc0, 0, 0, 0);
                sc1 = __builtin_amdgcn_mfma_f32_16x16x32_bf16(qf[f][0], kf[1][0], sc1, 0, 0, 0);
                sc1 = __builtin_amdgcn_mfma_f32_16x16x32_bf16(qf[f][1], kf[1][1], sc1, 0, 0, 0);

                float pa[4], pb[4];
                if (diag) {
                    // diagonal tile: k0 == qrowA. frag0: half0 triangular,
                    // half1 fully masked. frag1: half0 full, half1 triangular.
#pragma unroll
                    for (int r = 0; r < 4; ++r) {
                        const int rr = quad * 4 + r;       // row within frag
                        if (f == 0) {
                            pa[r] = (l15 <= rr) ? EXP2F(sc0[r] * sc_l2e) : 0.f;
                            pb[r] = 0.f;
                        } else {
                            pa[r] = EXP2F(sc0[r] * sc_l2e);
                            pb[r] = (l15 <= rr) ? EXP2F(sc1[r] * sc_l2e) : 0.f;
                        }
                    }
                } else {
#pragma unroll
                    for (int r = 0; r < 4; ++r) {
                        pa[r] = EXP2F(sc0[r] * sc_l2e);
                        pb[r] = EXP2F(sc1[r] * sc_l2e);
                    }
                }
#pragma unroll
                for (int r = 0; r < 4; ++r)
                    lsum[f][r] += pa[r] + pb[r];

                // wave-private P roundtrip (C-layout write -> A-layout read)
                short* pw = Pbuf[wave][f];
                asm volatile("" ::: "memory");
#pragma unroll
                for (int r = 0; r < 4; ++r) {
                    const int row = quad * 4 + r;
                    pw[row * 40 + l15]      = (short)f2bf(pa[r]);
                    pw[row * 40 + 16 + l15] = (short)f2bf(pb[r]);
                }
                asm volatile("" ::: "memory");
                const bf16x8 pf = *(const bf16x8*)(&pw[l15 * 40 + quad * 8]);

#pragma unroll
                for (int j = 0; j < 4; ++j)
                    acc[f][j] = __builtin_amdgcn_mfma_f32_16x16x32_bf16(pf, vfr[j], acc[f][j], 0, 0, 0);
            }
        }
    }

    // one-time 16-lane reduction of l partials
#pragma unroll
    for (int off = 1; off <= 8; off <<= 1)
#pragma unroll
        for (int f = 0; f < 2; ++f)
#pragma unroll
            for (int r = 0; r < 4; ++r)
                lsum[f][r] += __shfl_xor(lsum[f][r], off);

    const int b = bh >> 4;        // 0 in per-batch mode (gridDim.x == 16)
    const int h = bh & 15;
#pragma unroll
    for (int f = 0; f < 2; ++f) {
#pragma unroll
        for (int r = 0; r < 4; ++r) {
            const float invL = 1.0f / lsum[f][r];
            const int qrow = qrowA + f * 16 + quad * 4 + r;
            const size_t rowaddr = ((size_t)(b * SEQ + qrow)) * DM + h * DH;
#pragma unroll
            for (int j = 0; j < 4; ++j)
                ctx[rowaddr + j * 16 + l15] = f2bf(acc[f][j][r] * invL);
        }
    }
}

// ---------------------------------------------------------------------------
extern "C" void kernel_launch(void* const* d_in, const int* in_sizes, int n_in,
                              void* d_out, int out_size, void* d_ws, size_t ws_size,
                              hipStream_t stream)
{
    // Locate tensors by element count (immune to ordering / mask omission).
    auto find = [&](long want, int fb) -> const void* {
        for (int i = 0; i < n_in; ++i)
            if ((long)in_sizes[i] == want) return d_in[i];
        if (fb >= n_in) fb = n_in - 1;
        return d_in[fb];
    };
    const void* x     = find(8388608, 0);   // [4,2048,1024]
    const void* w_qkv = find(3145728, 2);   // [3072,1024]
    const void* b_qkv = find(3072,    3);   // [3072]
    const void* w_out = find(1048576, 4);   // [1024,1024]
    const void* b_out = find(1024,    5);   // [1024]

    char* ws   = (char*)d_ws;
    int*  flag = (int*)ws;
    char* p    = ws + 256;

    u16* xbf    = (u16*)p;                 p += (size_t)8388608 * 2;
    u16* wqkvbf = (u16*)p;                 p += (size_t)3145728 * 2;
    u16* bqkvbf = (u16*)p;                 p += 8192;
    u16* woutbf = (u16*)p;                 p += (size_t)1048576 * 2;
    u16* boutbf = (u16*)p;                 p += 8192;

    const size_t tensor_bytes = (size_t)M_TOT * DM * sizeof(u16);   // 16.78 MB
    const size_t chunk_bytes  = tensor_bytes / NUM_B;               // 4.19 MB
    const size_t conv_end     = (size_t)(p - ws);

    // ONE fused launch replaces detect + 5 converts (R16, verified win).
    convert_all<<<2048, 256, 0, stream>>>(
        x, w_qkv, b_qkv, w_out, b_out,
        xbf, wqkvbf, bqkvbf, woutbf, boutbf, flag);

    if (ws_size >= conv_end + 4 * tensor_bytes) {
        u16* Qb  = (u16*)(ws + conv_end);
        u16* Kb  = (u16*)(ws + conv_end + tensor_bytes);
        u16* Vb  = (u16*)(ws + conv_end + 2 * tensor_bytes);
        u16* ctx = (u16*)(ws + conv_end + 3 * tensor_bytes);

        gemm_bt<0, 3072><<<dim3(24, 64), 256, 0, stream>>>(
            xbf, wqkvbf, bqkvbf, Qb, Kb, Vb, nullptr, 0);
        attn_fwd<<<dim3(NUM_B * NH, SEQ / 128), 256, 0, stream>>>(Qb, Kb, Vb, ctx);
        gemm_bt<1, 1024><<<dim3(8, 64), 256, 0, stream>>>(
            ctx, woutbf, boutbf, d_out, nullptr, nullptr, flag, 0);
    } else {
        u16* Qb  = (u16*)(ws + conv_end);
        u16* Kb  = (u16*)(ws + conv_end + chunk_bytes);
        u16* Vb  = (u16*)(ws + conv_end + 2 * chunk_bytes);
        u16* ctx = (u16*)(ws + conv_end + 3 * chunk_bytes);
        for (int b = 0; b < NUM_B; ++b) {
            const long eoff = (long)b * SEQ * DM;
            gemm_bt<0, 3072><<<dim3(24, 16), 256, 0, stream>>>(
                xbf + eoff, wqkvbf, bqkvbf, Qb, Kb, Vb, nullptr, 0);
            attn_fwd<<<dim3(NH, SEQ / 128), 256, 0, stream>>>(Qb, Kb, Vb, ctx);
            gemm_bt<1, 1024><<<dim3(8, 16), 256, 0, stream>>>(
                ctx, woutbf, boutbf, d_out, nullptr, nullptr, flag, eoff);
        }
    }
}

// Round 9
// 320.242 us; speedup vs baseline: 1.0189x; 1.0189x over previous
//
#include <hip/hip_runtime.h>
#include <stdint.h>

typedef __attribute__((ext_vector_type(8))) short bf16x8;   // 8 bf16 = 4 VGPRs
typedef __attribute__((ext_vector_type(4))) float f32x4;
typedef unsigned short u16;

#define NUM_B 4
#define SEQ   2048
#define DM    1024
#define NH    16
#define DH    64
#define M_TOT (NUM_B * SEQ)   // 8192

__device__ __forceinline__ float bf2f(u16 u) {
    union { unsigned int i; float f; } c; c.i = ((unsigned int)u) << 16; return c.f;
}
__device__ __forceinline__ u16 f2bf(float f) {
    union { float f; unsigned int i; } c; c.f = f;
    unsigned int u = c.i;
    return (u16)((u + 0x7FFFu + ((u >> 16) & 1u)) >> 16);  // RNE
}
__device__ __forceinline__ unsigned int pack2(float a, float b) {
    return (unsigned int)f2bf(a) | ((unsigned int)f2bf(b) << 16);
}

#if __has_builtin(__builtin_amdgcn_exp2f)
#define EXP2F __builtin_amdgcn_exp2f
#else
#define EXP2F exp2f
#endif

#define GLOAD_LDS16(g, l)                                                     \
    __builtin_amdgcn_global_load_lds(                                         \
        (const __attribute__((address_space(1))) void*)(g),                   \
        (__attribute__((address_space(3))) void*)(l), 16, 0, 0)

// ---------------------------------------------------------------------------
// R16 (verified win): fused detect + 5-tensor convert in ONE launch.
// ---------------------------------------------------------------------------
__global__ void convert_all(const void* __restrict__ x,
                            const void* __restrict__ wqkv,
                            const void* __restrict__ bqkv,
                            const void* __restrict__ wout,
                            const void* __restrict__ bout,
                            u16* __restrict__ xb, u16* __restrict__ wqkvb,
                            u16* __restrict__ bqkvb, u16* __restrict__ woutb,
                            u16* __restrict__ boutb, int* __restrict__ flag)
{
    // --- per-block dtype detection (R4-verified heuristic) ---
    __shared__ int cnt;
    if (threadIdx.x == 0) cnt = 0;
    __syncthreads();
    int local = 0;
    const u16* xs = (const u16*)x;
    for (int i = threadIdx.x; i < 4096; i += 256) {
        const u16 v = xs[i];
        const int e = (v >> 7) & 0xFF;
        if (v == 0 || (e >= 110 && e <= 145)) local++;
    }
    atomicAdd(&cnt, local);
    __syncthreads();
    const int isf32 = (cnt >= 3686) ? 0 : 1;   // 0 = bf16 inputs, 1 = fp32
    if (blockIdx.x == 0 && threadIdx.x == 0) *flag = isf32;

    // --- 5-segment virtual index space, unit = 8 elements (16 B out) ---
    const long U0 = 1048576;           // x      8388608 elems
    const long U1 = U0 + 393216;       // w_qkv  3145728
    const long U2 = U1 + 384;          // b_qkv  3072
    const long U3 = U2 + 131072;       // w_out  1048576
    const long U4 = U3 + 128;          // b_out  1024

    for (long u = (long)blockIdx.x * 256 + threadIdx.x; u < U4;
         u += (long)gridDim.x * 256) {
        const void* src; u16* dst; long off;
        if (u < U0)      { src = x;    dst = xb;    off = u; }
        else if (u < U1) { src = wqkv; dst = wqkvb; off = u - U0; }
        else if (u < U2) { src = bqkv; dst = bqkvb; off = u - U1; }
        else if (u < U3) { src = wout; dst = woutb; off = u - U2; }
        else             { src = bout; dst = boutb; off = u - U3; }
        const long i = off * 8;
        if (isf32) {
            const float* f = (const float*)src;
            float4 a = *(const float4*)(f + i);
            float4 b = *(const float4*)(f + i + 4);
            uint4 o;
            o.x = pack2(a.x, a.y); o.y = pack2(a.z, a.w);
            o.z = pack2(b.x, b.y); o.w = pack2(b.z, b.w);
            *(uint4*)(dst + i) = o;
        } else {
            *(uint4*)(dst + i) = ((const uint4*)src)[off];
        }
    }
}

// ---------------------------------------------------------------------------
// bf16 GEMM — R18: R14/R16 verified single-buffered body (100.6 us) + XCD-
// chunked block mapping for MODE 0 (T1), guarded on gridDim.y==64.
// R17 post-mortem: BK=64 regressed (occupancy 25->17.5%) — m132 reproduced.
// R18 theory: kernel is exposed-staging-latency-bound; with x-major dispatch
// the ~80 concurrent blocks per XCD span ~27 grid rows -> per-XCD working
// set ~13 MB >> 4 MB L2 -> staging misses to L3/HBM feed the barrier drain.
// Remap (bijective, 1536 = 8 XCD x 12 col x 16 row) so each XCD owns a
// contiguous 12x16 chunk, x-fastest: working set ~4.8 MB ~= L2. Pure index
// permutation; worst case ~neutral (m160: -2%).
// ---------------------------------------------------------------------------
template <int MODE, int N_TOT>
__global__ __launch_bounds__(256) void gemm_bt(
    const u16* __restrict__ A, const u16* __restrict__ Bm,
    const u16* __restrict__ bias,
    void* __restrict__ out0v, u16* __restrict__ out1, u16* __restrict__ out2,
    const int* __restrict__ outf32, long out_off)
{
    __shared__ __align__(16) u16 As[128 * 32];
    __shared__ __align__(16) u16 Bs[128 * 32];
    const int K = 1024;

    const int tid  = threadIdx.x;
    const int wave = tid >> 6;
    const int lane = tid & 63;
    const int l15  = lane & 15;
    const int quad = lane >> 4;

    int bx = blockIdx.x, by = blockIdx.y;
    if (MODE == 0 && gridDim.x == 24 && gridDim.y == 64) {
        // XCD-chunk swizzle: dispatch-linear id -> (xcd = lin%8, w) -> tile
        // in that XCD's contiguous 12x16 chunk (x-fastest). Bijective.
        const int lin = by * 24 + bx;
        const int xcd = lin & 7;
        const int w   = lin >> 3;              // 0..191
        bx = (xcd & 1) * 12 + (w % 12);        // column
        by = (xcd >> 1) * 16 + (w / 12);       // row
    }
    const int m0 = by * 128;
    const int n0 = bx * 128;
    const int wm = (wave >> 1) * 64;
    const int wn = (wave & 1) * 64;

    const int srow = lane >> 2;
    const int soff = (lane & 3) * 8;

    f32x4 acc[4][4];
#pragma unroll
    for (int i = 0; i < 4; ++i)
#pragma unroll
        for (int j = 0; j < 4; ++j)
            acc[i][j] = (f32x4){0.f, 0.f, 0.f, 0.f};

    for (int k0 = 0; k0 < K; k0 += 32) {
#pragma unroll
        for (int r = 0; r < 2; ++r) {
            const int chunk = wave * 2 + r;
            const int row   = chunk * 16 + srow;
            GLOAD_LDS16(&A[(size_t)(m0 + row) * K + k0 + soff], &As[chunk * 512]);
            GLOAD_LDS16(&Bm[(size_t)(n0 + row) * K + k0 + soff], &Bs[chunk * 512]);
        }
        __syncthreads();

        bf16x8 af[4], bfv[4];
#pragma unroll
        for (int i = 0; i < 4; ++i)
            af[i] = *(const bf16x8*)(&As[(wm + i * 16 + l15) * 32 + quad * 8]);
#pragma unroll
        for (int j = 0; j < 4; ++j)
            bfv[j] = *(const bf16x8*)(&Bs[(wn + j * 16 + l15) * 32 + quad * 8]);

#pragma unroll
        for (int i = 0; i < 4; ++i)
#pragma unroll
            for (int j = 0; j < 4; ++j)
                acc[i][j] = __builtin_amdgcn_mfma_f32_16x16x32_bf16(
                    af[i], bfv[j], acc[i][j], 0, 0, 0);
        __syncthreads();
    }

    const int of32 = outf32 ? *outf32 : 0;
#pragma unroll
    for (int j = 0; j < 4; ++j) {
        const int n  = n0 + wn + j * 16 + l15;
        const float bv = bf2f(bias[n]);
#pragma unroll
        for (int i = 0; i < 4; ++i) {
#pragma unroll
            for (int reg = 0; reg < 4; ++reg) {
                const int m = m0 + wm + i * 16 + quad * 4 + reg;
                const float v = acc[i][j][reg] + bv;
                if (MODE == 0) {
                    const int sel = n >> 10;         // 0=Q 1=K 2=V
                    const int h   = (n >> 6) & 15;
                    const int dh  = n & 63;
                    const int b   = m >> 11;
                    const int s   = m & 2047;
                    if (sel == 2) {
                        out2[((size_t)((b * NH + h) * DH + dh)) * SEQ + s] = f2bf(v);
                    } else {
                        u16* dst = (sel == 0) ? (u16*)out0v : out1;
                        dst[((size_t)((b * NH + h) * SEQ + s)) * DH + dh] = f2bf(v);
                    }
                } else {
                    if (of32)
                        ((float*)out0v)[out_off + (size_t)m * N_TOT + n] = v;
                    else
                        ((u16*)out0v)[out_off + (size_t)m * N_TOT + n] = f2bf(v);
                }
            }
        }
    }
}

// ---------------------------------------------------------------------------
// Flash attention, causal — R14 (verified best). R9 structure + CU
// load-balance y-permutation + exp2 fold. UNCHANGED.
// ---------------------------------------------------------------------------
__global__ __launch_bounds__(256) void attn_fwd(
    const u16* __restrict__ Qb, const u16* __restrict__ Kb,
    const u16* __restrict__ Vt, u16* __restrict__ ctx)
{
    __shared__ __align__(16) u16 Ks[2][2048];          // fragment-major K tile
    __shared__ __align__(16) u16 Vs[2][2048];          // fragment-major V tile
    __shared__ __align__(16) short Pbuf[4][2][16 * 40];

    const int tid  = threadIdx.x;
    const int wave = tid >> 6;
    const int lane = tid & 63;
    const int l15  = lane & 15;
    const int quad = lane >> 4;

    const int bh = blockIdx.x;
    // CU load-balance permutation of the q-tile index (bijective on 0..15):
    // {a, a+4, a+8, a+12} -> {a, 7-a, 8+a, 15-a}; per-CU staged-tile sum
    // becomes 136 for every CU (was 112..160).
    const int ya = blockIdx.y & 3, yk = blockIdx.y >> 2;
    const int yb = (yk == 0) ? ya : (yk == 1) ? 7 - ya : (yk == 2) ? 8 + ya : 15 - ya;

    const int q0 = yb * 128;                  // block's 128 q-rows
    const int qrowA = q0 + wave * 32;         // wave's frag-0 rows
    const size_t base  = (size_t)bh * SEQ * DH;   // Q,K
    const size_t baseT = (size_t)bh * DH * SEQ;   // Vt
    const float sc_l2e = 0.18033688011112042f;    // (1/8) * log2(e)

    // Q fragments: [frag][dh-half]
    bf16x8 qf[2][2];
#pragma unroll
    for (int f = 0; f < 2; ++f)
#pragma unroll
        for (int c = 0; c < 2; ++c)
            qf[f][c] = *(const bf16x8*)(&Qb[base + (size_t)(qrowA + f * 16 + l15) * DH + c * 32 + quad * 8]);

    f32x4 acc[2][4];
#pragma unroll
    for (int f = 0; f < 2; ++f)
#pragma unroll
        for (int j = 0; j < 4; ++j) acc[f][j] = (f32x4){0.f, 0.f, 0.f, 0.f};
    float lsum[2][4] = {{0.f, 0.f, 0.f, 0.f}, {0.f, 0.f, 0.f, 0.f}};

    const int ktend = yb * 4 + 3;     // block-uniform trip count
    const int mkt   = yb * 4 + wave;  // wave's diagonal tile (k0 == qrowA)

    // staging source offsets (fragment-major; see R9 header)
    const int k_r = (wave & 1) * 16 + l15;            // key row within tile
    const int k_c = ((wave >> 1) * 4 + quad) * 8;     // dh elem offset
    const int v_dh = wave * 16 + l15;                 // dh row
    const int v_k  = quad * 8;                        // key elem offset

    {   // stage tile 0 into buf 0
        GLOAD_LDS16(&Kb[base + (size_t)k_r * DH + k_c], &Ks[0][wave * 512]);
        GLOAD_LDS16(&Vt[baseT + (size_t)v_dh * SEQ + v_k], &Vs[0][wave * 512]);
    }

    for (int kt = 0; kt <= ktend; ++kt) {
        const int cur = kt & 1;
        __syncthreads();   // drains stage(kt) DMA + prior ds_reads of cur buf

        if (kt + 1 <= ktend) {   // prefetch next tile into the other buffer
            const int nk0 = (kt + 1) * 32;
            GLOAD_LDS16(&Kb[base + (size_t)(nk0 + k_r) * DH + k_c],
                        &Ks[1 - cur][wave * 512]);
            GLOAD_LDS16(&Vt[baseT + (size_t)v_dh * SEQ + nk0 + v_k],
                        &Vs[1 - cur][wave * 512]);
        }

        if (kt <= mkt) {         // wave-uniform causal skip
            // fragment reads: all lane-consecutive b128 (conflict-free)
            bf16x8 kf[2][2], vfr[4];
#pragma unroll
            for (int half = 0; half < 2; ++half)
#pragma unroll
                for (int c = 0; c < 2; ++c)
                    kf[half][c] = *(const bf16x8*)(&Ks[cur][(c * 2 + half) * 512 + lane * 8]);
#pragma unroll
            for (int j = 0; j < 4; ++j)
                vfr[j] = *(const bf16x8*)(&Vs[cur][j * 512 + lane * 8]);

            const int diag = (kt == mkt);
#pragma unroll
            for (int f = 0; f < 2; ++f) {
                f32x4 sc0 = (f32x4){0.f, 0.f, 0.f, 0.f};
                f32x4 sc1 = (f32x4){0.f, 0.f, 0.f, 0.f};
                sc0 = __builtin_amdgcn_mfma_f32_16x16x32_bf16(qf[f][0], kf[0][0], sc0, 0, 0, 0);
                sc0 = __builtin_amdgcn_mfma_f32_16x16x32_bf16(qf[f][1], kf[0][1], sc0, 0, 0, 0);
                sc1 = __builtin_amdgcn_mfma_f32_16x16x32_bf16(qf[f][0], kf[1][0], sc1, 0, 0, 0);
                sc1 = __builtin_amdgcn_mfma_f32_16x16x32_bf16(qf[f][1], kf[1][1], sc1, 0, 0, 0);

                float pa[4], pb[4];
                if (diag) {
                    // diagonal tile: k0 == qrowA. frag0: half0 triangular,
                    // half1 fully masked. frag1: half0 full, half1 triangular.
#pragma unroll
                    for (int r = 0; r < 4; ++r) {
                        const int rr = quad * 4 + r;       // row within frag
                        if (f == 0) {
                            pa[r] = (l15 <= rr) ? EXP2F(sc0[r] * sc_l2e) : 0.f;
                            pb[r] = 0.f;
                        } else {
                            pa[r] = EXP2F(sc0[r] * sc_l2e);
                            pb[r] = (l15 <= rr) ? EXP2F(sc1[r] * sc_l2e) : 0.f;
                        }
                    }
                } else {
#pragma unroll
                    for (int r = 0; r < 4; ++r) {
                        pa[r] = EXP2F(sc0[r] * sc_l2e);
                        pb[r] = EXP2F(sc1[r] * sc_l2e);
                    }
                }
#pragma unroll
                for (int r = 0; r < 4; ++r)
                    lsum[f][r] += pa[r] + pb[r];

                // wave-private P roundtrip (C-layout write -> A-layout read)
                short* pw = Pbuf[wave][f];
                asm volatile("" ::: "memory");
#pragma unroll
                for (int r = 0; r < 4; ++r) {
                    const int row = quad * 4 + r;
                    pw[row * 40 + l15]      = (short)f2bf(pa[r]);
                    pw[row * 40 + 16 + l15] = (short)f2bf(pb[r]);
                }
                asm volatile("" ::: "memory");
                const bf16x8 pf = *(const bf16x8*)(&pw[l15 * 40 + quad * 8]);

#pragma unroll
                for (int j = 0; j < 4; ++j)
                    acc[f][j] = __builtin_amdgcn_mfma_f32_16x16x32_bf16(pf, vfr[j], acc[f][j], 0, 0, 0);
            }
        }
    }

    // one-time 16-lane reduction of l partials
#pragma unroll
    for (int off = 1; off <= 8; off <<= 1)
#pragma unroll
        for (int f = 0; f < 2; ++f)
#pragma unroll
            for (int r = 0; r < 4; ++r)
                lsum[f][r] += __shfl_xor(lsum[f][r], off);

    const int b = bh >> 4;        // 0 in per-batch mode (gridDim.x == 16)
    const int h = bh & 15;
#pragma unroll
    for (int f = 0; f < 2; ++f) {
#pragma unroll
        for (int r = 0; r < 4; ++r) {
            const float invL = 1.0f / lsum[f][r];
            const int qrow = qrowA + f * 16 + quad * 4 + r;
            const size_t rowaddr = ((size_t)(b * SEQ + qrow)) * DM + h * DH;
#pragma unroll
            for (int j = 0; j < 4; ++j)
                ctx[rowaddr + j * 16 + l15] = f2bf(acc[f][j][r] * invL);
        }
    }
}

// ---------------------------------------------------------------------------
extern "C" void kernel_launch(void* const* d_in, const int* in_sizes, int n_in,
                              void* d_out, int out_size, void* d_ws, size_t ws_size,
                              hipStream_t stream)
{
    // Locate tensors by element count (immune to ordering / mask omission).
    auto find = [&](long want, int fb) -> const void* {
        for (int i = 0; i < n_in; ++i)
            if ((long)in_sizes[i] == want) return d_in[i];
        if (fb >= n_in) fb = n_in - 1;
        return d_in[fb];
    };
    const void* x     = find(8388608, 0);   // [4,2048,1024]
    const void* w_qkv = find(3145728, 2);   // [3072,1024]
    const void* b_qkv = find(3072,    3);   // [3072]
    const void* w_out = find(1048576, 4);   // [1024,1024]
    const void* b_out = find(1024,    5);   // [1024]

    char* ws   = (char*)d_ws;
    int*  flag = (int*)ws;
    char* p    = ws + 256;

    u16* xbf    = (u16*)p;                 p += (size_t)8388608 * 2;
    u16* wqkvbf = (u16*)p;                 p += (size_t)3145728 * 2;
    u16* bqkvbf = (u16*)p;                 p += 8192;
    u16* woutbf = (u16*)p;                 p += (size_t)1048576 * 2;
    u16* boutbf = (u16*)p;                 p += 8192;

    const size_t tensor_bytes = (size_t)M_TOT * DM * sizeof(u16);   // 16.78 MB
    const size_t chunk_bytes  = tensor_bytes / NUM_B;               // 4.19 MB
    const size_t conv_end     = (size_t)(p - ws);

    // ONE fused launch replaces detect + 5 converts (R16, verified win).
    convert_all<<<2048, 256, 0, stream>>>(
        x, w_qkv, b_qkv, w_out, b_out,
        xbf, wqkvbf, bqkvbf, woutbf, boutbf, flag);

    if (ws_size >= conv_end + 4 * tensor_bytes) {
        u16* Qb  = (u16*)(ws + conv_end);
        u16* Kb  = (u16*)(ws + conv_end + tensor_bytes);
        u16* Vb  = (u16*)(ws + conv_end + 2 * tensor_bytes);
        u16* ctx = (u16*)(ws + conv_end + 3 * tensor_bytes);

        gemm_bt<0, 3072><<<dim3(24, 64), 256, 0, stream>>>(
            xbf, wqkvbf, bqkvbf, Qb, Kb, Vb, nullptr, 0);
        attn_fwd<<<dim3(NUM_B * NH, SEQ / 128), 256, 0, stream>>>(Qb, Kb, Vb, ctx);
        gemm_bt<1, 1024><<<dim3(8, 64), 256, 0, stream>>>(
            ctx, woutbf, boutbf, d_out, nullptr, nullptr, flag, 0);
    } else {
        u16* Qb  = (u16*)(ws + conv_end);
        u16* Kb  = (u16*)(ws + conv_end + chunk_bytes);
        u16* Vb  = (u16*)(ws + conv_end + 2 * chunk_bytes);
        u16* ctx = (u16*)(ws + conv_end + 3 * chunk_bytes);
        for (int b = 0; b < NUM_B; ++b) {
            const long eoff = (long)b * SEQ * DM;
            gemm_bt<0, 3072><<<dim3(24, 16), 256, 0, stream>>>(
                xbf + eoff, wqkvbf, bqkvbf, Qb, Kb, Vb, nullptr, 0);
            attn_fwd<<<dim3(NH, SEQ / 128), 256, 0, stream>>>(Qb, Kb, Vb, ctx);
            gemm_bt<1, 1024><<<dim3(8, 16), 256, 0, stream>>>(
                ctx, woutbf, boutbf, d_out, nullptr, nullptr, flag, eoff);
        }
    }
}

// Round 10
// 312.453 us; speedup vs baseline: 1.0443x; 1.0249x over previous
//
#include <hip/hip_runtime.h>
#include <stdint.h>

typedef __attribute__((ext_vector_type(8))) short bf16x8;   // 8 bf16 = 4 VGPRs
typedef __attribute__((ext_vector_type(4))) float f32x4;
typedef unsigned short u16;

#define NUM_B 4
#define SEQ   2048
#define DM    1024
#define NH    16
#define DH    64
#define M_TOT (NUM_B * SEQ)   // 8192

__device__ __forceinline__ float bf2f(u16 u) {
    union { unsigned int i; float f; } c; c.i = ((unsigned int)u) << 16; return c.f;
}
__device__ __forceinline__ u16 f2bf(float f) {
    union { float f; unsigned int i; } c; c.f = f;
    unsigned int u = c.i;
    return (u16)((u + 0x7FFFu + ((u >> 16) & 1u)) >> 16);  // RNE
}
__device__ __forceinline__ unsigned int pack2(float a, float b) {
    return (unsigned int)f2bf(a) | ((unsigned int)f2bf(b) << 16);
}

#if __has_builtin(__builtin_amdgcn_exp2f)
#define EXP2F __builtin_amdgcn_exp2f
#else
#define EXP2F exp2f
#endif

#define GLOAD_LDS16(g, l)                                                     \
    __builtin_amdgcn_global_load_lds(                                         \
        (const __attribute__((address_space(1))) void*)(g),                   \
        (__attribute__((address_space(3))) void*)(l), 16, 0, 0)

// ---------------------------------------------------------------------------
// R16 (verified win): fused detect + 5-tensor convert in ONE launch.
// ---------------------------------------------------------------------------
__global__ void convert_all(const void* __restrict__ x,
                            const void* __restrict__ wqkv,
                            const void* __restrict__ bqkv,
                            const void* __restrict__ wout,
                            const void* __restrict__ bout,
                            u16* __restrict__ xb, u16* __restrict__ wqkvb,
                            u16* __restrict__ bqkvb, u16* __restrict__ woutb,
                            u16* __restrict__ boutb, int* __restrict__ flag)
{
    // --- per-block dtype detection (R4-verified heuristic) ---
    __shared__ int cnt;
    if (threadIdx.x == 0) cnt = 0;
    __syncthreads();
    int local = 0;
    const u16* xs = (const u16*)x;
    for (int i = threadIdx.x; i < 4096; i += 256) {
        const u16 v = xs[i];
        const int e = (v >> 7) & 0xFF;
        if (v == 0 || (e >= 110 && e <= 145)) local++;
    }
    atomicAdd(&cnt, local);
    __syncthreads();
    const int isf32 = (cnt >= 3686) ? 0 : 1;   // 0 = bf16 inputs, 1 = fp32
    if (blockIdx.x == 0 && threadIdx.x == 0) *flag = isf32;

    // --- 5-segment virtual index space, unit = 8 elements (16 B out) ---
    const long U0 = 1048576;           // x      8388608 elems
    const long U1 = U0 + 393216;       // w_qkv  3145728
    const long U2 = U1 + 384;          // b_qkv  3072
    const long U3 = U2 + 131072;       // w_out  1048576
    const long U4 = U3 + 128;          // b_out  1024

    for (long u = (long)blockIdx.x * 256 + threadIdx.x; u < U4;
         u += (long)gridDim.x * 256) {
        const void* src; u16* dst; long off;
        if (u < U0)      { src = x;    dst = xb;    off = u; }
        else if (u < U1) { src = wqkv; dst = wqkvb; off = u - U0; }
        else if (u < U2) { src = bqkv; dst = bqkvb; off = u - U1; }
        else if (u < U3) { src = wout; dst = woutb; off = u - U2; }
        else             { src = bout; dst = boutb; off = u - U3; }
        const long i = off * 8;
        if (isf32) {
            const float* f = (const float*)src;
            float4 a = *(const float4*)(f + i);
            float4 b = *(const float4*)(f + i + 4);
            uint4 o;
            o.x = pack2(a.x, a.y); o.y = pack2(a.z, a.w);
            o.z = pack2(b.x, b.y); o.w = pack2(b.z, b.w);
            *(uint4*)(dst + i) = o;
        } else {
            *(uint4*)(dst + i) = ((const uint4*)src)[off];
        }
    }
}

// ---------------------------------------------------------------------------
// bf16 GEMM — R19: exact R14/R16 verified form (100.6 us), swizzle REVERTED.
// R18 post-mortem: XCD-chunk swizzle cut FETCH 71.8->41.1 MB (mechanism
// real) but WRITE rose 52->84 MB (partial-line eviction on the 2B-scatter
// epilogue: x-major dispatch had co-scheduled the blocks sharing output
// lines) -> net -7%. Decision rule: FETCH down + dur flat proves the stall
// is intrinsic 2-phase barrier/drain cost, not cache misses. With R15
// (dbuf null) and R17 (BK=64 regression), the 128^2/2-phase structure is
// measured at its floor (~510 TF @ K=1024); only the 8-phase template
// would move it (out of scope after 0/6 on structural rewrites).
// MODE 0: scatter Q,K -> [bh][s][dh]; V -> transposed [bh][dh][s].
// MODE 1: plain store, fp32 or bf16 per *outf32.
// ---------------------------------------------------------------------------
template <int MODE, int N_TOT>
__global__ __launch_bounds__(256) void gemm_bt(
    const u16* __restrict__ A, const u16* __restrict__ Bm,
    const u16* __restrict__ bias,
    void* __restrict__ out0v, u16* __restrict__ out1, u16* __restrict__ out2,
    const int* __restrict__ outf32, long out_off)
{
    __shared__ __align__(16) u16 As[128 * 32];
    __shared__ __align__(16) u16 Bs[128 * 32];
    const int K = 1024;

    const int tid  = threadIdx.x;
    const int wave = tid >> 6;
    const int lane = tid & 63;
    const int l15  = lane & 15;
    const int quad = lane >> 4;

    const int m0 = blockIdx.y * 128;
    const int n0 = blockIdx.x * 128;
    const int wm = (wave >> 1) * 64;
    const int wn = (wave & 1) * 64;

    const int srow = lane >> 2;
    const int soff = (lane & 3) * 8;

    f32x4 acc[4][4];
#pragma unroll
    for (int i = 0; i < 4; ++i)
#pragma unroll
        for (int j = 0; j < 4; ++j)
            acc[i][j] = (f32x4){0.f, 0.f, 0.f, 0.f};

    for (int k0 = 0; k0 < K; k0 += 32) {
#pragma unroll
        for (int r = 0; r < 2; ++r) {
            const int chunk = wave * 2 + r;
            const int row   = chunk * 16 + srow;
            GLOAD_LDS16(&A[(size_t)(m0 + row) * K + k0 + soff], &As[chunk * 512]);
            GLOAD_LDS16(&Bm[(size_t)(n0 + row) * K + k0 + soff], &Bs[chunk * 512]);
        }
        __syncthreads();

        bf16x8 af[4], bfv[4];
#pragma unroll
        for (int i = 0; i < 4; ++i)
            af[i] = *(const bf16x8*)(&As[(wm + i * 16 + l15) * 32 + quad * 8]);
#pragma unroll
        for (int j = 0; j < 4; ++j)
            bfv[j] = *(const bf16x8*)(&Bs[(wn + j * 16 + l15) * 32 + quad * 8]);

#pragma unroll
        for (int i = 0; i < 4; ++i)
#pragma unroll
            for (int j = 0; j < 4; ++j)
                acc[i][j] = __builtin_amdgcn_mfma_f32_16x16x32_bf16(
                    af[i], bfv[j], acc[i][j], 0, 0, 0);
        __syncthreads();
    }

    const int of32 = outf32 ? *outf32 : 0;
#pragma unroll
    for (int j = 0; j < 4; ++j) {
        const int n  = n0 + wn + j * 16 + l15;
        const float bv = bf2f(bias[n]);
#pragma unroll
        for (int i = 0; i < 4; ++i) {
#pragma unroll
            for (int reg = 0; reg < 4; ++reg) {
                const int m = m0 + wm + i * 16 + quad * 4 + reg;
                const float v = acc[i][j][reg] + bv;
                if (MODE == 0) {
                    const int sel = n >> 10;         // 0=Q 1=K 2=V
                    const int h   = (n >> 6) & 15;
                    const int dh  = n & 63;
                    const int b   = m >> 11;
                    const int s   = m & 2047;
                    if (sel == 2) {
                        out2[((size_t)((b * NH + h) * DH + dh)) * SEQ + s] = f2bf(v);
                    } else {
                        u16* dst = (sel == 0) ? (u16*)out0v : out1;
                        dst[((size_t)((b * NH + h) * SEQ + s)) * DH + dh] = f2bf(v);
                    }
                } else {
                    if (of32)
                        ((float*)out0v)[out_off + (size_t)m * N_TOT + n] = v;
                    else
                        ((u16*)out0v)[out_off + (size_t)m * N_TOT + n] = f2bf(v);
                }
            }
        }
    }
}

// ---------------------------------------------------------------------------
// Flash attention, causal — R14 (verified best). R9 structure + CU
// load-balance y-permutation + exp2 fold. UNCHANGED.
// ---------------------------------------------------------------------------
__global__ __launch_bounds__(256) void attn_fwd(
    const u16* __restrict__ Qb, const u16* __restrict__ Kb,
    const u16* __restrict__ Vt, u16* __restrict__ ctx)
{
    __shared__ __align__(16) u16 Ks[2][2048];          // fragment-major K tile
    __shared__ __align__(16) u16 Vs[2][2048];          // fragment-major V tile
    __shared__ __align__(16) short Pbuf[4][2][16 * 40];

    const int tid  = threadIdx.x;
    const int wave = tid >> 6;
    const int lane = tid & 63;
    const int l15  = lane & 15;
    const int quad = lane >> 4;

    const int bh = blockIdx.x;
    // CU load-balance permutation of the q-tile index (bijective on 0..15):
    // {a, a+4, a+8, a+12} -> {a, 7-a, 8+a, 15-a}; per-CU staged-tile sum
    // becomes 136 for every CU (was 112..160).
    const int ya = blockIdx.y & 3, yk = blockIdx.y >> 2;
    const int yb = (yk == 0) ? ya : (yk == 1) ? 7 - ya : (yk == 2) ? 8 + ya : 15 - ya;

    const int q0 = yb * 128;                  // block's 128 q-rows
    const int qrowA = q0 + wave * 32;         // wave's frag-0 rows
    const size_t base  = (size_t)bh * SEQ * DH;   // Q,K
    const size_t baseT = (size_t)bh * DH * SEQ;   // Vt
    const float sc_l2e = 0.18033688011112042f;    // (1/8) * log2(e)

    // Q fragments: [frag][dh-half]
    bf16x8 qf[2][2];
#pragma unroll
    for (int f = 0; f < 2; ++f)
#pragma unroll
        for (int c = 0; c < 2; ++c)
            qf[f][c] = *(const bf16x8*)(&Qb[base + (size_t)(qrowA + f * 16 + l15) * DH + c * 32 + quad * 8]);

    f32x4 acc[2][4];
#pragma unroll
    for (int f = 0; f < 2; ++f)
#pragma unroll
        for (int j = 0; j < 4; ++j) acc[f][j] = (f32x4){0.f, 0.f, 0.f, 0.f};
    float lsum[2][4] = {{0.f, 0.f, 0.f, 0.f}, {0.f, 0.f, 0.f, 0.f}};

    const int ktend = yb * 4 + 3;     // block-uniform trip count
    const int mkt   = yb * 4 + wave;  // wave's diagonal tile (k0 == qrowA)

    // staging source offsets (fragment-major; see R9 header)
    const int k_r = (wave & 1) * 16 + l15;            // key row within tile
    const int k_c = ((wave >> 1) * 4 + quad) * 8;     // dh elem offset
    const int v_dh = wave * 16 + l15;                 // dh row
    const int v_k  = quad * 8;                        // key elem offset

    {   // stage tile 0 into buf 0
        GLOAD_LDS16(&Kb[base + (size_t)k_r * DH + k_c], &Ks[0][wave * 512]);
        GLOAD_LDS16(&Vt[baseT + (size_t)v_dh * SEQ + v_k], &Vs[0][wave * 512]);
    }

    for (int kt = 0; kt <= ktend; ++kt) {
        const int cur = kt & 1;
        __syncthreads();   // drains stage(kt) DMA + prior ds_reads of cur buf

        if (kt + 1 <= ktend) {   // prefetch next tile into the other buffer
            const int nk0 = (kt + 1) * 32;
            GLOAD_LDS16(&Kb[base + (size_t)(nk0 + k_r) * DH + k_c],
                        &Ks[1 - cur][wave * 512]);
            GLOAD_LDS16(&Vt[baseT + (size_t)v_dh * SEQ + nk0 + v_k],
                        &Vs[1 - cur][wave * 512]);
        }

        if (kt <= mkt) {         // wave-uniform causal skip
            // fragment reads: all lane-consecutive b128 (conflict-free)
            bf16x8 kf[2][2], vfr[4];
#pragma unroll
            for (int half = 0; half < 2; ++half)
#pragma unroll
                for (int c = 0; c < 2; ++c)
                    kf[half][c] = *(const bf16x8*)(&Ks[cur][(c * 2 + half) * 512 + lane * 8]);
#pragma unroll
            for (int j = 0; j < 4; ++j)
                vfr[j] = *(const bf16x8*)(&Vs[cur][j * 512 + lane * 8]);

            const int diag = (kt == mkt);
#pragma unroll
            for (int f = 0; f < 2; ++f) {
                f32x4 sc0 = (f32x4){0.f, 0.f, 0.f, 0.f};
                f32x4 sc1 = (f32x4){0.f, 0.f, 0.f, 0.f};
                sc0 = __builtin_amdgcn_mfma_f32_16x16x32_bf16(qf[f][0], kf[0][0], sc0, 0, 0, 0);
                sc0 = __builtin_amdgcn_mfma_f32_16x16x32_bf16(qf[f][1], kf[0][1], sc0, 0, 0, 0);
                sc1 = __builtin_amdgcn_mfma_f32_16x16x32_bf16(qf[f][0], kf[1][0], sc1, 0, 0, 0);
                sc1 = __builtin_amdgcn_mfma_f32_16x16x32_bf16(qf[f][1], kf[1][1], sc1, 0, 0, 0);

                float pa[4], pb[4];
                if (diag) {
                    // diagonal tile: k0 == qrowA. frag0: half0 triangular,
                    // half1 fully masked. frag1: half0 full, half1 triangular.
#pragma unroll
                    for (int r = 0; r < 4; ++r) {
                        const int rr = quad * 4 + r;       // row within frag
                        if (f == 0) {
                            pa[r] = (l15 <= rr) ? EXP2F(sc0[r] * sc_l2e) : 0.f;
                            pb[r] = 0.f;
                        } else {
                            pa[r] = EXP2F(sc0[r] * sc_l2e);
                            pb[r] = (l15 <= rr) ? EXP2F(sc1[r] * sc_l2e) : 0.f;
                        }
                    }
                } else {
#pragma unroll
                    for (int r = 0; r < 4; ++r) {
                        pa[r] = EXP2F(sc0[r] * sc_l2e);
                        pb[r] = EXP2F(sc1[r] * sc_l2e);
                    }
                }
#pragma unroll
                for (int r = 0; r < 4; ++r)
                    lsum[f][r] += pa[r] + pb[r];

                // wave-private P roundtrip (C-layout write -> A-layout read)
                short* pw = Pbuf[wave][f];
                asm volatile("" ::: "memory");
#pragma unroll
                for (int r = 0; r < 4; ++r) {
                    const int row = quad * 4 + r;
                    pw[row * 40 + l15]      = (short)f2bf(pa[r]);
                    pw[row * 40 + 16 + l15] = (short)f2bf(pb[r]);
                }
                asm volatile("" ::: "memory");
                const bf16x8 pf = *(const bf16x8*)(&pw[l15 * 40 + quad * 8]);

#pragma unroll
                for (int j = 0; j < 4; ++j)
                    acc[f][j] = __builtin_amdgcn_mfma_f32_16x16x32_bf16(pf, vfr[j], acc[f][j], 0, 0, 0);
            }
        }
    }

    // one-time 16-lane reduction of l partials
#pragma unroll
    for (int off = 1; off <= 8; off <<= 1)
#pragma unroll
        for (int f = 0; f < 2; ++f)
#pragma unroll
            for (int r = 0; r < 4; ++r)
                lsum[f][r] += __shfl_xor(lsum[f][r], off);

    const int b = bh >> 4;        // 0 in per-batch mode (gridDim.x == 16)
    const int h = bh & 15;
#pragma unroll
    for (int f = 0; f < 2; ++f) {
#pragma unroll
        for (int r = 0; r < 4; ++r) {
            const float invL = 1.0f / lsum[f][r];
            const int qrow = qrowA + f * 16 + quad * 4 + r;
            const size_t rowaddr = ((size_t)(b * SEQ + qrow)) * DM + h * DH;
#pragma unroll
            for (int j = 0; j < 4; ++j)
                ctx[rowaddr + j * 16 + l15] = f2bf(acc[f][j][r] * invL);
        }
    }
}

// ---------------------------------------------------------------------------
extern "C" void kernel_launch(void* const* d_in, const int* in_sizes, int n_in,
                              void* d_out, int out_size, void* d_ws, size_t ws_size,
                              hipStream_t stream)
{
    // Locate tensors by element count (immune to ordering / mask omission).
    auto find = [&](long want, int fb) -> const void* {
        for (int i = 0; i < n_in; ++i)
            if ((long)in_sizes[i] == want) return d_in[i];
        if (fb >= n_in) fb = n_in - 1;
        return d_in[fb];
    };
    const void* x     = find(8388608, 0);   // [4,2048,1024]
    const void* w_qkv = find(3145728, 2);   // [3072,1024]
    const void* b_qkv = find(3072,    3);   // [3072]
    const void* w_out = find(1048576, 4);   // [1024,1024]
    const void* b_out = find(1024,    5);   // [1024]

    char* ws   = (char*)d_ws;
    int*  flag = (int*)ws;
    char* p    = ws + 256;

    u16* xbf    = (u16*)p;                 p += (size_t)8388608 * 2;
    u16* wqkvbf = (u16*)p;                 p += (size_t)3145728 * 2;
    u16* bqkvbf = (u16*)p;                 p += 8192;
    u16* woutbf = (u16*)p;                 p += (size_t)1048576 * 2;
    u16* boutbf = (u16*)p;                 p += 8192;

    const size_t tensor_bytes = (size_t)M_TOT * DM * sizeof(u16);   // 16.78 MB
    const size_t chunk_bytes  = tensor_bytes / NUM_B;               // 4.19 MB
    const size_t conv_end     = (size_t)(p - ws);

    // ONE fused launch replaces detect + 5 converts (R16, verified win).
    convert_all<<<2048, 256, 0, stream>>>(
        x, w_qkv, b_qkv, w_out, b_out,
        xbf, wqkvbf, bqkvbf, woutbf, boutbf, flag);

    if (ws_size >= conv_end + 4 * tensor_bytes) {
        u16* Qb  = (u16*)(ws + conv_end);
        u16* Kb  = (u16*)(ws + conv_end + tensor_bytes);
        u16* Vb  = (u16*)(ws + conv_end + 2 * tensor_bytes);
        u16* ctx = (u16*)(ws + conv_end + 3 * tensor_bytes);

        gemm_bt<0, 3072><<<dim3(24, 64), 256, 0, stream>>>(
            xbf, wqkvbf, bqkvbf, Qb, Kb, Vb, nullptr, 0);
        attn_fwd<<<dim3(NUM_B * NH, SEQ / 128), 256, 0, stream>>>(Qb, Kb, Vb, ctx);
        gemm_bt<1, 1024><<<dim3(8, 64), 256, 0, stream>>>(
            ctx, woutbf, boutbf, d_out, nullptr, nullptr, flag, 0);
    } else {
        u16* Qb  = (u16*)(ws + conv_end);
        u16* Kb  = (u16*)(ws + conv_end + chunk_bytes);
        u16* Vb  = (u16*)(ws + conv_end + 2 * chunk_bytes);
        u16* ctx = (u16*)(ws + conv_end + 3 * chunk_bytes);
        for (int b = 0; b < NUM_B; ++b) {
            const long eoff = (long)b * SEQ * DM;
            gemm_bt<0, 3072><<<dim3(24, 16), 256, 0, stream>>>(
                xbf + eoff, wqkvbf, bqkvbf, Qb, Kb, Vb, nullptr, 0);
            attn_fwd<<<dim3(NH, SEQ / 128), 256, 0, stream>>>(Qb, Kb, Vb, ctx);
            gemm_bt<1, 1024><<<dim3(8, 16), 256, 0, stream>>>(
                ctx, woutbf, boutbf, d_out, nullptr, nullptr, flag, eoff);
        }
    }
}